// Round 9
// baseline (223.611 us; speedup 1.0000x reference)
//
#include <hip/hip_runtime.h>

#define T_ 512
#define C_ 4096
#define L_ 128
#define RCPLN2 1.4426950408889634f
#define LN2 0.6931471805599453f
#define NEGL (-1e30f)

// raw base-2 transcendentals: single v_exp_f32 / v_log_f32
__device__ __forceinline__ float fexp2(float x) { return __builtin_amdgcn_exp2f(x); }
__device__ __forceinline__ float flog2(float x) { return __builtin_amdgcn_logf(x); }
__device__ __forceinline__ float lg(float x)    { return (x > 0.f) ? flog2(x) : NEGL; }

// ---- DPP cross-lane (VALU pipe; ctrl must be an immediate) ----
template <int CTRL>
__device__ __forceinline__ float dppmov(float v) {
  return __int_as_float(__builtin_amdgcn_update_dpp(
      0, __float_as_int(v), CTRL, 0xF, 0xF, true));
}
__device__ __forceinline__ float wshr1(float v) { return dppmov<0x138>(v); }  // shfl_up 1, lane0<-0
__device__ __forceinline__ float wshl1(float v) { return dppmov<0x130>(v); }  // shfl_down 1, lane63<-0
template <int CTRL>
__device__ __forceinline__ float maxdpp(float v) { return fmaxf(v, dppmov<CTRL>(v)); }
__device__ __forceinline__ float wavemax(float v) {   // nonneg v, uniform result
  v = maxdpp<0xB1>(v);  v = maxdpp<0x4E>(v);  v = maxdpp<0x141>(v);
  v = maxdpp<0x140>(v); v = maxdpp<0x142>(v); v = maxdpp<0x143>(v);
  return __int_as_float(__builtin_amdgcn_readlane(__float_as_int(v), 63));
}

// One block per (b,t) row: stream row -> LDS + sum exp2; gather 129 label cols.
__global__ __launch_bounds__(256) void k_lse_gather(
    const float* __restrict__ scores, const int* __restrict__ labels,
    const int* __restrict__ feat_lens,
    float* __restrict__ p_lab, float* __restrict__ p_blank) {
  const int row = blockIdx.x;           // b*T + t
  const int b = row >> 9;               // T_ == 512
  const int t = row & (T_ - 1);
  if (t >= feat_lens[b]) return;        // frozen rows never read by DP

  __shared__ float sRow[C_];
  __shared__ float sSum[4];
  const float4* __restrict__ rp4 = (const float4*)(scores + (size_t)row * C_);
  float4* sRow4 = (float4*)sRow;
  const int tid = threadIdx.x;

  float s0 = 0.f, s1 = 0.f, s2 = 0.f, s3 = 0.f;
#pragma unroll
  for (int k = 0; k < 4; ++k) {
    float4 v = rp4[tid + 256 * k];
    sRow4[tid + 256 * k] = v;
    s0 += fexp2(v.x * RCPLN2);
    s1 += fexp2(v.y * RCPLN2);
    s2 += fexp2(v.z * RCPLN2);
    s3 += fexp2(v.w * RCPLN2);
  }
  float s = (s0 + s1) + (s2 + s3);
#pragma unroll
  for (int off = 32; off; off >>= 1) s += __shfl_down(s, off);
  const int wid = tid >> 6, lane = tid & 63;
  if (lane == 0) sSum[wid] = s;
  __syncthreads();
  const float l2sum = flog2((sSum[0] + sSum[1]) + (sSum[2] + sSum[3]));

  if (tid < L_) {
    const int lab = labels[b * L_ + tid];                  // 1..C-1
    p_lab[(size_t)row * L_ + tid] = fexp2(sRow[lab] * RCPLN2 - l2sum);
  } else if (tid == L_) {
    p_blank[row] = fexp2(sRow[0] * RCPLN2 - l2sum);
  }
}

// exact pow2 rescale: center wave max at 2^72; S_i tracks true=val*2^S_i
#define RESC5(x0,x1,x2,x3,x4,xp,Si) {                                   \
    const float mm = wavemax(fmaxf(fmaxf(fmaxf(x0,x1),fmaxf(x2,x3)),x4)); \
    const int Eb = (__float_as_int(mm) >> 23) & 0xFF;                   \
    const int d = max(Eb - 199, -127);                                  \
    const float rr = __int_as_float((127 - d) << 23);                   \
    Si += d;                                                            \
    x0 *= rr; x1 *= rr; x2 *= rr; x3 *= rr; x4 *= rr; xp *= rr; }
#define RESC6(x0,x1,x2,x3,x4,xq0,xq1,Si) {                              \
    const float mm = wavemax(fmaxf(fmaxf(fmaxf(x0,x1),fmaxf(x2,x3)),x4)); \
    const int Eb = (__float_as_int(mm) >> 23) & 0xFF;                   \
    const int d = max(Eb - 199, -127);                                  \
    const float rr = __int_as_float((127 - d) << 23);                   \
    Si += d;                                                            \
    x0 *= rr; x1 *= rr; x2 *= rr; x3 *= rr; x4 *= rr; xq0 *= rr; xq1 *= rr; }

#define LOADF(Sc, Sb_, TS) _Pragma("unroll")                            \
  for (int k = 0; k < 8; ++k) { Sc[k] = llp[(TS + k) * 64 + lane]; Sb_[k] = lbp[TS + k]; }
#define LOADB(Sc, Sb_, TS) _Pragma("unroll")                            \
  for (int k = 0; k < 8; ++k) { Sc[k] = llp[(TS - k) * 64 + lane]; Sb_[k] = lbp[TS - k]; }

#define FCHUNK(Sc, Sb_, TS) _Pragma("unroll")                           \
  for (int k = 0; k < 8; ++k) {                                         \
    if (TS + k <= tm) {                                                 \
      const float n3 = Sc[k].y * (a3 + a2 + (skip3 ? a1 : 0.f));        \
      const float n4 = Sb_[k] * (a4 + a3);                              \
      const float pn = wshr1(n3);                                       \
      const float n0 = Sb_[k] * (a0 + p);                               \
      const float n1 = Sc[k].x * (a1 + a0 + (skip1 ? p : 0.f));         \
      const float n2 = Sb_[k] * (a2 + a1);                              \
      a0 = n0; a1 = n1; a2 = n2; a3 = n3;                               \
      a4 = (lane == 63) ? n4 : 0.f; p = pn;                             \
    }                                                                   \
    if (k & 1) RESC5(a0, a1, a2, a3, a4, p, Sa_i)                       \
  }

#define BCHUNK(Sc, Sb_, TS) _Pragma("unroll")                           \
  for (int k = 0; k < 8; ++k) {                                         \
    if (TS - k >= tm) {                                                 \
      const float n0 = Sb_[k] * (b0 + b1);                              \
      const float n1 = Sc[k].x * (b1 + b2 + (skip3 ? b3 : 0.f));        \
      const float n4 = Sb_[k] * b4;                                     \
      const float q0n = wshl1(n0);                                      \
      const float q1n = wshl1(n1);                                      \
      const float n3 = Sc[k].y * (b3 + q0 + (skipd ? q1 : 0.f));        \
      const float n2 = Sb_[k] * (b2 + b3);                              \
      b0 = n0; b1 = n1; b2 = n2; b3 = n3; b4 = n4;                      \
      q0 = (lane == 63) ? n4 : q0n; q1 = q1n;                           \
    }                                                                   \
    if (k & 1) RESC6(b0, b1, b2, b3, b4, q0, q1, Sb_i)                  \
  }

// One block (2 waves) per batch. Wave0 fwd alpha 0..tm, wave1 bwd beta
// flen-1..tm. Prob space + exact pow2 max-rescale every 2 steps. 8-step
// chunks, 4 register slots, 3-chunk prefetch depth (covers ~HBM latency).
// Midpoint combine in log2 space. Last block reduces the batch mean.
__global__ __launch_bounds__(128) void k_ctc_dp(
    const float* __restrict__ p_lab, const float* __restrict__ p_blank,
    const int* __restrict__ labels, const int* __restrict__ feat_lens,
    const int* __restrict__ label_lens, float* __restrict__ loss_out,
    int* __restrict__ counter, float* __restrict__ out, int B) {
  const int b = blockIdx.x;
  const int lane = threadIdx.x & 63;
  const int wid = threadIdx.x >> 6;
  const int flen = feat_lens[b];
  const int llen = label_lens[b];     // 64..128 per setup
  const int tm = (flen >> 1) & ~1;    // even meeting point >= 192

  const int l0 = labels[b * L_ + 2 * lane];       // state 4l+1
  const int l1 = labels[b * L_ + 2 * lane + 1];   // state 4l+3
  const int lm1 = __shfl_up(l1, 1);
  const int ln0 = __shfl_down(l0, 1);
  const bool skip1 = (lane > 0) && (l0 != lm1);
  const bool skip3 = (l1 != l0);
  const bool skipd = (lane < 63) && (ln0 != l1);

  const float2* __restrict__ llp = (const float2*)(p_lab + (size_t)b * T_ * L_);
  const float* __restrict__ lpl = p_lab + (size_t)b * T_ * L_;
  const float* __restrict__ lbp = p_blank + b * T_;

  __shared__ float sB[257];   // log2(beta_hat[s]) at tm
  __shared__ int sSbI;        // backward scale (log2, integer-exact)

  if (wid == 0) {
    // ---------------- forward ----------------
    const float2 ll0 = llp[lane];
    float a0 = (lane == 0) ? lbp[0] : 0.f;
    float a1 = (lane == 0) ? ll0.x : 0.f;
    float a2 = 0.f, a3 = 0.f, a4 = 0.f;
    float p = 0.f;
    int Sa_i = 0;

    float2 Ac[8], Bc[8], Cc[8], Dc[8];
    float  Ab[8], Bb[8], Cb[8], Db[8];
    LOADF(Ac, Ab, 1) LOADF(Bc, Bb, 9) LOADF(Cc, Cb, 17)
    int t = 1;
    while (t <= tm) {                 // prefetch stays <= tm+55 <= flen-1
      LOADF(Dc, Db, t + 24) FCHUNK(Ac, Ab, t)
      LOADF(Ac, Ab, t + 32) FCHUNK(Bc, Bb, t + 8)
      LOADF(Bc, Bb, t + 40) FCHUNK(Cc, Cb, t + 16)
      LOADF(Cc, Cb, t + 48) FCHUNK(Dc, Db, t + 24)
      t += 32;
    }
    // ---- midpoint combine in log2 space ----
    const float2 cce = llp[tm * 64 + lane];
    const float cbe = lbp[tm];
    const float lb2 = flog2(cbe), lc0 = flog2(cce.x), lc1 = flog2(cce.y);
    const float la0 = lg(a0), la1 = lg(a1), la2 = lg(a2), la3 = lg(a3);
    const float la4 = lg(a4);
    __syncthreads();                   // wave1 published sB + sSbI
    float w0 = la0 + sB[4 * lane + 0] - lb2;
    float w1 = la1 + sB[4 * lane + 1] - lc0;
    float w2 = la2 + sB[4 * lane + 2] - lb2;
    float w3 = la3 + sB[4 * lane + 3] - lc1;
    float m = fmaxf(fmaxf(w0, w1), fmaxf(w2, w3));
    float w4 = NEGL;
    if (lane == 63) { w4 = la4 + sB[256] - lb2; m = fmaxf(m, w4); }
#pragma unroll
    for (int off = 1; off < 64; off <<= 1) m = fmaxf(m, __shfl_xor(m, off));
    float sum = fexp2(w0 - m) + fexp2(w1 - m) + fexp2(w2 - m) + fexp2(w3 - m);
    if (lane == 63) sum += fexp2(w4 - m);
#pragma unroll
    for (int off = 1; off < 64; off <<= 1) sum += __shfl_xor(sum, off);
    if (lane == 0) {
      const float l2lik = m + flog2(sum) + (float)(Sa_i + sSbI);
      float loss = -LN2 * l2lik;
      if (loss > 0.5e30f || !(loss == loss)) loss = 0.0f;   // zero_infinity
      const float lb = loss / (float)llen;
      __hip_atomic_store(&loss_out[b], lb, __ATOMIC_RELEASE,
                         __HIP_MEMORY_SCOPE_AGENT);
      const int old = __hip_atomic_fetch_add(counter, 1, __ATOMIC_ACQ_REL,
                                             __HIP_MEMORY_SCOPE_AGENT);
      if (old == B - 1) {              // last block: batch mean
        float tot = 0.f;
        for (int i = 0; i < B; ++i)
          tot += __hip_atomic_load(&loss_out[i], __ATOMIC_ACQUIRE,
                                   __HIP_MEMORY_SCOPE_AGENT);
        out[0] = tot / (float)B;
      }
    }
  } else {
    // ---------------- backward ----------------
    const int e = 2 * llen;                        // 128..256, even
    const float ve = lbp[flen - 1];
    const float vo = lpl[(size_t)(flen - 1) * L_ + (llen - 1)];
    float b0 = (4 * lane == e) ? ve : 0.f;
    float b1 = (4 * lane + 1 == e - 1) ? vo : 0.f;
    float b2 = (4 * lane + 2 == e) ? ve : 0.f;
    float b3 = (4 * lane + 3 == e - 1) ? vo : 0.f;
    float b4 = (lane == 63 && e == 256) ? ve : 0.f;
    float q0 = __shfl_down(b0, 1); q0 = (lane == 63) ? b4 : q0;
    float q1 = __shfl_down(b1, 1); q1 = (lane == 63) ? 0.f : q1;
    int Sb_i = 0;

    float2 Ac[8], Bc[8], Cc[8], Dc[8];
    float  Ab[8], Bb[8], Cb[8], Db[8];
    int t = flen - 2;
    LOADB(Ac, Ab, t) LOADB(Bc, Bb, t - 8) LOADB(Cc, Cb, t - 16)
    while (t >= tm) {                 // prefetch stays >= tm-55 >= 0
      LOADB(Dc, Db, t - 24) BCHUNK(Ac, Ab, t)
      LOADB(Ac, Ab, t - 32) BCHUNK(Bc, Bb, t - 8)
      LOADB(Bc, Bb, t - 40) BCHUNK(Cc, Cb, t - 16)
      LOADB(Cc, Cb, t - 48) BCHUNK(Dc, Db, t - 24)
      t -= 32;
    }
    sB[4 * lane + 0] = lg(b0);
    sB[4 * lane + 1] = lg(b1);
    sB[4 * lane + 2] = lg(b2);
    sB[4 * lane + 3] = lg(b3);
    if (lane == 63) sB[256] = lg(b4);
    if (lane == 0) sSbI = Sb_i;
    __syncthreads();
  }
}

extern "C" void kernel_launch(void* const* d_in, const int* in_sizes, int n_in,
                              void* d_out, int out_size, void* d_ws, size_t ws_size,
                              hipStream_t stream) {
  const float* scores = (const float*)d_in[0];
  const int* labels = (const int*)d_in[1];
  const int* feat_lens = (const int*)d_in[2];
  const int* label_lens = (const int*)d_in[3];
  const int B = in_sizes[2];

  float* p_lab = (float*)d_ws;                            // B*T*L floats (4 MB)
  float* p_blank = p_lab + (size_t)B * T_ * L_;           // B*T floats
  float* loss_out = p_blank + (size_t)B * T_;             // B floats
  int* counter = (int*)(loss_out + B);                    // 1 int
  float* out = (float*)d_out;

  hipMemsetAsync(counter, 0, sizeof(int), stream);        // capture-safe
  k_lse_gather<<<B * T_, 256, 0, stream>>>(scores, labels, feat_lens, p_lab, p_blank);
  k_ctc_dp<<<B, 128, 0, stream>>>(p_lab, p_blank, labels, feat_lens, label_lens,
                                  loss_out, counter, out, B);
}